// Round 10
// baseline (406.418 us; speedup 1.0000x reference)
//
#include <hip/hip_runtime.h>
#include <hip/hip_bf16.h>

typedef __bf16 bf16;
typedef __attribute__((ext_vector_type(8))) __bf16 bf16x8;
typedef __attribute__((ext_vector_type(4))) float f32x4;

#define DEV static __device__ __forceinline__

namespace {

constexpr int B = 4, N = 1024, D = 1024, H = 16, DH = 64;
constexpr int R2 = 2 * N - 1;   // 2047
constexpr int BH = B * H;       // 64
constexpr float SCL = 0.03125f; // 1/sqrt(1024)

// manual RNE f32 -> bf16 (scalar use)
DEV bf16 f2b(float x) {
  unsigned u = __builtin_bit_cast(unsigned, x);
  unsigned r = u + 0x7FFFu + ((u >> 16) & 1u);
  unsigned short h = (unsigned short)(r >> 16);
  return __builtin_bit_cast(bf16, h);
}

// HW packed cvt: 2 f32 -> 2 bf16 in one VALU op
DEV unsigned cvtpk(float lo, float hi) {
  unsigned r;
  asm("v_cvt_pk_bf16_f32 %0, %1, %2" : "=v"(r) : "v"(lo), "v"(hi));
  return r;
}

DEV bf16x8 cvt8pk(float4 a, float4 b) {
  union { unsigned u[4]; bf16x8 v; } r;
  r.u[0] = cvtpk(a.x, a.y); r.u[1] = cvtpk(a.z, a.w);
  r.u[2] = cvtpk(b.x, b.y); r.u[3] = cvtpk(b.z, b.w);
  return r.v;
}

DEV f32x4 mfma16(bf16x8 a, bf16x8 b, f32x4 c) {
  return __builtin_amdgcn_mfma_f32_16x16x32_bf16(a, b, c, 0, 0, 0);
}

// nontemporal 16B store via clang-native vector type
DEV void nt_store4(float4 v, float* p) {
  f32x4 x = {v.x, v.y, v.z, v.w};
  __builtin_nontemporal_store(x, reinterpret_cast<f32x4*>(p));
}

// LDS-only block barrier (no vmcnt drain)
DEV void block_sync_lds() {
  __builtin_amdgcn_sched_barrier(0);
  asm volatile("s_waitcnt lgkmcnt(0)" ::: "memory");
  __builtin_amdgcn_s_barrier();
  __builtin_amdgcn_sched_barrier(0);
}

// ---------- W transpose + cast: Wt[n][k] = bf16(W[k][n]) ----------
__global__ __launch_bounds__(256) void transpose_cast_w(
    const float* __restrict__ w0, const float* __restrict__ w1,
    const float* __restrict__ w2, const float* __restrict__ w3,
    const float* __restrict__ w4, bf16* __restrict__ t0, bf16* __restrict__ t1,
    bf16* __restrict__ t2, bf16* __restrict__ t3, bf16* __restrict__ t4) {
  const float* src; bf16* dst;
  switch (blockIdx.z) {
    case 0: src = w0; dst = t0; break;
    case 1: src = w1; dst = t1; break;
    case 2: src = w2; dst = t2; break;
    case 3: src = w3; dst = t3; break;
    default: src = w4; dst = t4; break;
  }
  __shared__ float tile[64][65];
  const int k0 = blockIdx.y * 64, n0 = blockIdx.x * 64;
  const int t = threadIdx.x, r = t >> 2, c0 = (t & 3) * 16;
  const float4* sp = reinterpret_cast<const float4*>(src + (size_t)(k0 + r) * D + n0 + c0);
#pragma unroll
  for (int q = 0; q < 4; ++q) {
    float4 v = sp[q];
    tile[r][c0 + q * 4 + 0] = v.x; tile[r][c0 + q * 4 + 1] = v.y;
    tile[r][c0 + q * 4 + 2] = v.z; tile[r][c0 + q * 4 + 3] = v.w;
  }
  __syncthreads();
  union { unsigned u[8]; uint4 q[2]; } pk;
#pragma unroll
  for (int e = 0; e < 8; ++e)
    pk.u[e] = cvtpk(tile[c0 + 2 * e][r], tile[c0 + 2 * e + 1][r]);
  uint4* dp = reinterpret_cast<uint4*>(dst + (size_t)(n0 + r) * D + k0 + c0);
  dp[0] = pk.q[0]; dp[1] = pk.q[1];
}

// ---------- projection GEMM core: C[128x128] tile of A[M x 1024] @ Bt^T -----
// T2 XOR-swizzled LDS; reg prefetch (loads fly across LDS-only barriers);
// coalesced epilogues via f32 LDS (stride 132).
enum { M_QUV = 0, M_HEAD = 1, M_P = 2, M_OUT = 3, M_V = 4 };

template <bool ABF>
DEV void proj_core(char* smem, const void* __restrict__ Av,
                   const bf16* __restrict__ Bt, int M, int mt, int nt, int mode,
                   const float* __restrict__ bias, const float* __restrict__ ubp,
                   const float* __restrict__ vbp, bf16* __restrict__ dst0,
                   bf16* __restrict__ dst1, float* __restrict__ outf) {
  bf16* As = (bf16*)smem;
  bf16* Bs = (bf16*)(smem + 16384);
  float* ep = (float*)smem;  // aliased epilogue buffer, stride 132
  const int t = threadIdx.x;
  const int m0 = mt * 128, n0 = nt * 128;
  const int lane = t & 63, w = t >> 6;
  const int wi = w >> 1, wj = w & 1;
  const int fr = lane & 15, g = lane >> 4;
  f32x4 acc[4][4] = {};

  int rowc[4], ccc[4], rmc[4];
#pragma unroll
  for (int it = 0; it < 4; ++it) {
    const int chunk = it * 256 + t;
    rowc[it] = chunk >> 3; ccc[it] = chunk & 7;
    int rm = m0 + rowc[it]; rmc[it] = rm < M ? rm : M - 1;
  }
  float4 raf[4][2];
  bf16x8 rab[4];
  bf16x8 rbb[4];
  auto loadstep = [&](int k0) {
#pragma unroll
    for (int it = 0; it < 4; ++it) {
      if (ABF) {
        rab[it] = *reinterpret_cast<const bf16x8*>(
            (const bf16*)Av + (size_t)rmc[it] * D + k0 + ccc[it] * 8);
      } else {
        const float4* ap = reinterpret_cast<const float4*>(
            (const float*)Av + (size_t)rmc[it] * D + k0 + ccc[it] * 8);
        raf[it][0] = ap[0]; raf[it][1] = ap[1];
      }
      rbb[it] = *reinterpret_cast<const bf16x8*>(
          Bt + (size_t)(n0 + rowc[it]) * D + k0 + ccc[it] * 8);
    }
  };

  loadstep(0);
  for (int k0 = 0; k0 < D; k0 += 64) {
#pragma unroll
    for (int it = 0; it < 4; ++it) {
      const int row = rowc[it], cc = ccc[it];
      bf16x8 av;
      if (ABF) av = rab[it]; else av = cvt8pk(raf[it][0], raf[it][1]);
      *reinterpret_cast<bf16x8*>(&As[row * 64 + ((cc ^ (row & 7)) << 3)]) = av;
      *reinterpret_cast<bf16x8*>(&Bs[row * 64 + ((cc ^ (row & 7)) << 3)]) =
          rbb[it];
    }
    block_sync_lds();
    if (k0 + 64 < D) loadstep(k0 + 64);  // in flight across the next barrier
#pragma unroll
    for (int ks = 0; ks < 2; ++ks) {
      bf16x8 fa[4], fb[4];
#pragma unroll
      for (int i = 0; i < 4; ++i) {
        const int row = wi * 64 + i * 16 + fr;
        fa[i] = *reinterpret_cast<const bf16x8*>(
            &As[row * 64 + (((ks * 4 + g) ^ (row & 7)) << 3)]);
      }
#pragma unroll
      for (int j = 0; j < 4; ++j) {
        const int row = wj * 64 + j * 16 + fr;
        fb[j] = *reinterpret_cast<const bf16x8*>(
            &Bs[row * 64 + (((ks * 4 + g) ^ (row & 7)) << 3)]);
      }
#pragma unroll
      for (int i = 0; i < 4; ++i)
#pragma unroll
        for (int j = 0; j < 4; ++j) acc[i][j] = mfma16(fa[i], fb[j], acc[i][j]);
    }
    block_sync_lds();
  }
  // ---- epilogue: 2 passes of 64 rows via f32 LDS (stride 132), coalesced ----
#pragma unroll
  for (int p = 0; p < 2; ++p) {
    block_sync_lds();
    if (wi == p) {
#pragma unroll
      for (int i = 0; i < 4; ++i)
#pragma unroll
        for (int j = 0; j < 4; ++j)
#pragma unroll
          for (int q = 0; q < 4; ++q)
            ep[(i * 16 + g * 4 + q) * 132 + wj * 64 + j * 16 + fr] =
                acc[i][j][q];
    }
    block_sync_lds();
    if (mode == M_V) {
      // transposed write: Vt[bh][dh][token], 64B contiguous per thread
      const int col = t >> 1, seg = t & 1;
      const int cg = n0 + col;
      const int h_ = cg >> 6, dh = cg & 63;
      const int b_ = m0 >> 10;
      const int tok0 = (m0 & 1023) + p * 64 + seg * 32;
      const float bvv = bias[cg];
      unsigned pk[16];
#pragma unroll
      for (int e = 0; e < 16; ++e) {
        const float v0 = ep[(seg * 32 + 2 * e + 0) * 132 + col] + bvv;
        const float v1 = ep[(seg * 32 + 2 * e + 1) * 132 + col] + bvv;
        pk[e] = cvtpk(v0, v1);
      }
      bf16* dp = dst0 + ((size_t)(b_ * H + h_) * DH + dh) * N + tok0;
#pragma unroll
      for (int kk = 0; kk < 4; ++kk)
        reinterpret_cast<uint4*>(dp)[kk] =
            *reinterpret_cast<const uint4*>(&pk[kk * 4]);
      continue;
    }
    const int lr = t >> 2, cl = (t & 3) * 32;
    const int m = m0 + p * 64 + lr;
    if (m < M) {
      float v[32];
#pragma unroll
      for (int kk = 0; kk < 8; ++kk) {
        const float4 f =
            *reinterpret_cast<const float4*>(&ep[lr * 132 + cl + kk * 4]);
        v[kk * 4 + 0] = f.x; v[kk * 4 + 1] = f.y;
        v[kk * 4 + 2] = f.z; v[kk * 4 + 3] = f.w;
      }
      const int cg0 = n0 + cl;
      if (mode == M_OUT) {
        float* op = outf + (size_t)m * D + cg0;
#pragma unroll
        for (int kk = 0; kk < 8; ++kk) {
          float4 f = {v[kk * 4] + bias[cg0 + kk * 4],
                      v[kk * 4 + 1] + bias[cg0 + kk * 4 + 1],
                      v[kk * 4 + 2] + bias[cg0 + kk * 4 + 2],
                      v[kk * 4 + 3] + bias[cg0 + kk * 4 + 3]};
          nt_store4(f, op + kk * 4);
        }
      } else if (mode == M_P) {
        const int b_ = m / R2, r_ = m - b_ * R2;
        const int h_ = cg0 >> 6, dh0 = cg0 & 63;
        bf16* dp = dst0 + (((size_t)(b_ * H + h_)) * R2 + r_) * DH + dh0;
        unsigned pk[16];
#pragma unroll
        for (int e = 0; e < 16; ++e) pk[e] = cvtpk(v[2 * e], v[2 * e + 1]);
#pragma unroll
        for (int kk = 0; kk < 4; ++kk)
          reinterpret_cast<uint4*>(dp)[kk] =
              *reinterpret_cast<const uint4*>(&pk[kk * 4]);
      } else {
        const int b_ = m >> 10, ii = m & (N - 1);
        const int h_ = cg0 >> 6, dh0 = cg0 & 63;
        const size_t o = (((size_t)(b_ * H + h_)) * N + ii) * DH + dh0;
        if (mode == M_QUV) {
          unsigned pku[16], pkv[16];
#pragma unroll
          for (int e = 0; e < 16; ++e) {
            const float b0 = bias[cg0 + 2 * e], b1 = bias[cg0 + 2 * e + 1];
            pku[e] = cvtpk(v[2 * e] + b0 + ubp[cg0 + 2 * e],
                           v[2 * e + 1] + b1 + ubp[cg0 + 2 * e + 1]);
            pkv[e] = cvtpk(v[2 * e] + b0 + vbp[cg0 + 2 * e],
                           v[2 * e + 1] + b1 + vbp[cg0 + 2 * e + 1]);
          }
#pragma unroll
          for (int kk = 0; kk < 4; ++kk) {
            reinterpret_cast<uint4*>(dst0 + o)[kk] =
                *reinterpret_cast<const uint4*>(&pku[kk * 4]);
            reinterpret_cast<uint4*>(dst1 + o)[kk] =
                *reinterpret_cast<const uint4*>(&pkv[kk * 4]);
          }
        } else {
          unsigned pk[16];
#pragma unroll
          for (int e = 0; e < 16; ++e)
            pk[e] = cvtpk(v[2 * e] + bias[cg0 + 2 * e],
                          v[2 * e + 1] + bias[cg0 + 2 * e + 1]);
#pragma unroll
          for (int kk = 0; kk < 4; ++kk)
            reinterpret_cast<uint4*>(dst0 + o)[kk] =
                *reinterpret_cast<const uint4*>(&pk[kk * 4]);
        }
      }
    }
  }
}

// merged projections: grid (8, 32, 5); XCD x owns a contiguous M-chunk per
// z-slice. z: 0=Q(QUV) 1=K 2=V(->Vt direct) 3,4=P halves.
__global__ __launch_bounds__(256, 3) void proj_qkvp(
    const float* __restrict__ query, const float* __restrict__ key,
    const float* __restrict__ value, const float* __restrict__ pos_emb,
    const bf16* __restrict__ Wqt, const bf16* __restrict__ Wkt,
    const bf16* __restrict__ Wvt, const bf16* __restrict__ Wpt,
    const float* __restrict__ bq, const float* __restrict__ bk,
    const float* __restrict__ bv, const float* __restrict__ ub,
    const float* __restrict__ vbp, bf16* __restrict__ Qu,
    bf16* __restrict__ Qv, bf16* __restrict__ Kb, bf16* __restrict__ Vt,
    bf16* __restrict__ Pb) {
  __shared__ __align__(16) char smem[34048];
  const int z = blockIdx.z, x = blockIdx.x, y = blockIdx.y;
  const int nt = y & 7;
  const int mt = x * 4 + (y >> 3);
  switch (z) {
    case 0:
      proj_core<false>(smem, query, Wqt, B * N, mt, nt, M_QUV, bq, ub, vbp, Qu,
                       Qv, nullptr);
      break;
    case 1:
      proj_core<false>(smem, key, Wkt, B * N, mt, nt, M_HEAD, bk, nullptr,
                       nullptr, Kb, nullptr, nullptr);
      break;
    case 2:
      proj_core<false>(smem, value, Wvt, B * N, mt, nt, M_V, bv, nullptr,
                       nullptr, Vt, nullptr, nullptr);
      break;
    case 3:
      proj_core<false>(smem, pos_emb, Wpt, B * R2, mt, nt, M_P, nullptr,
                       nullptr, nullptr, Pb, nullptr, nullptr);
      break;
    default:
      proj_core<false>(smem, pos_emb, Wpt, B * R2, 32 + mt, nt, M_P, nullptr,
                       nullptr, nullptr, Pb, nullptr, nullptr);
      break;
  }
}

__global__ __launch_bounds__(256, 2) void proj_out(const bf16* __restrict__ OA,
                                                   const bf16* __restrict__ Wot,
                                                   const float* __restrict__ bo,
                                                   float* __restrict__ outF) {
  __shared__ __align__(16) char smem[34048];
  const int nt = blockIdx.y & 7;
  const int mt = blockIdx.x * 4 + (blockIdx.y >> 3);
  proj_core<true>(smem, OA, Wot, B * N, mt, nt, M_OUT, bo, nullptr, nullptr,
                  nullptr, nullptr, outF);
}

// ---------- fused: content + pos(shifted) + softmax + PV ---------------------
constexpr int RB = 16;

DEV int SIDX(int r, int c) {
  return r * 1024 + (((c >> 2) ^ (r & 7)) << 2) + (c & 3);
}

__global__ __launch_bounds__(512, 4) void fused_attn(
    const bf16* __restrict__ Qu, const bf16* __restrict__ Qv,
    const bf16* __restrict__ Kb, const bf16* __restrict__ Pb,
    const bf16* __restrict__ Vt, float* __restrict__ cont,
    float* __restrict__ posS, float* __restrict__ attn,
    bf16* __restrict__ OA) {
  __shared__ float sc[RB * 1024];  // 64 KB
  __shared__ float red[1024];      // PV partial reduce
  const int bid0 = blockIdx.y * 64 + blockIdx.x;
  const int bid = (bid0 & 7) * 512 + (bid0 >> 3);  // XCD owns 8 heads
  const int bh = bid >> 6, i0 = (bid & 63) * RB;
  const int t = threadIdx.x, lane = t & 63, w = t >> 6;
  const int fr = lane & 15, g = lane >> 4, kg = g * 8;

  // ---- phase 1: content scores -> sc ----
  {
    const bf16* Qub = Qu + ((size_t)bh * N + i0) * DH;
    const bf16* Kbh = Kb + (size_t)bh * N * DH;
    const bf16x8 fa0 = *reinterpret_cast<const bf16x8*>(Qub + (size_t)fr * DH + kg);
    const bf16x8 fa1 = *reinterpret_cast<const bf16x8*>(Qub + (size_t)fr * DH + 32 + kg);
#pragma unroll
    for (int tt = 0; tt < 8; ++tt) {
      const int ct = (w * 8 + tt) * 16;
      const bf16x8 fb0 =
          *reinterpret_cast<const bf16x8*>(Kbh + (size_t)(ct + fr) * DH + kg);
      const bf16x8 fb1 =
          *reinterpret_cast<const bf16x8*>(Kbh + (size_t)(ct + fr) * DH + 32 + kg);
      f32x4 acc = {};
      acc = mfma16(fa0, fb0, acc);
      acc = mfma16(fa1, fb1, acc);
      const int c = ct + fr;
#pragma unroll
      for (int q = 0; q < 4; ++q) sc[SIDX(g * 4 + q, c)] = acc[q];
    }
  }
  block_sync_lds();

  // ---- phase 2a: read content rows to regs (LDS only) ----
  float4 xc[2][4];
#pragma unroll
  for (int rr2 = 0; rr2 < 2; ++rr2) {
    const int r = w * 2 + rr2;
#pragma unroll
    for (int k = 0; k < 4; ++k) {
      const int ch = (k * 64 + lane) ^ (r & 7);
      xc[rr2][k] = *reinterpret_cast<const float4*>(&sc[r * 1024 + ch * 4]);
    }
  }
  block_sync_lds();

  // ---- phase 2b: issue cont stores (fly under MFMA); pos scores -> sc ----
  {
    float* contb = cont + ((size_t)bh * N + i0) * N;
#pragma unroll
    for (int rr2 = 0; rr2 < 2; ++rr2) {
      const int r = w * 2 + rr2;
#pragma unroll
      for (int k = 0; k < 4; ++k)
        nt_store4(xc[rr2][k], contb + (size_t)r * N + (k * 64 + lane) * 4);
    }
    const bf16* Qvb = Qv + ((size_t)bh * N + i0) * DH;
    const bf16* Pbh = Pb + (size_t)bh * R2 * DH;
    const bf16x8 fa0 = *reinterpret_cast<const bf16x8*>(Qvb + (size_t)fr * DH + kg);
    const bf16x8 fa1 = *reinterpret_cast<const bf16x8*>(Qvb + (size_t)fr * DH + 32 + kg);
    const int Rlo = (N - RB) - i0;
    for (int tt = w; tt < 65; tt += 8) {
      const int rr = Rlo + tt * 16 + fr;
      const int rc = rr < R2 ? rr : R2 - 1;
      const bf16x8 fb0 =
          *reinterpret_cast<const bf16x8*>(Pbh + (size_t)rc * DH + kg);
      const bf16x8 fb1 =
          *reinterpret_cast<const bf16x8*>(Pbh + (size_t)rc * DH + 32 + kg);
      f32x4 acc = {};
      acc = mfma16(fa0, fb0, acc);
      acc = mfma16(fa1, fb1, acc);
#pragma unroll
      for (int q = 0; q < 4; ++q) {
        const int r = g * 4 + q;
        const int jj = rr - (N - 1) + i0 + r;
        if (rr < R2 && jj >= 0 && jj < N) sc[SIDX(r, jj)] = acc[q];
      }
    }
  }
  block_sync_lds();

  // ---- phase 3: posS store; softmax(xc+xp); attn store; attn -> sc ----
  {
    float* posb = posS + ((size_t)bh * N + i0) * N;
    float* attnb = attn + ((size_t)bh * N + i0) * N;
#pragma unroll
    for (int rr2 = 0; rr2 < 2; ++rr2) {
      const int r = w * 2 + rr2;
      float4 xp[4], x[4];
      int ch[4];
#pragma unroll
      for (int k = 0; k < 4; ++k) {
        ch[k] = (k * 64 + lane) ^ (r & 7);
        xp[k] = *reinterpret_cast<const float4*>(&sc[r * 1024 + ch[k] * 4]);
      }
      float mx = -1e30f;
#pragma unroll
      for (int k = 0; k < 4; ++k) {
        nt_store4(xp[k], posb + (size_t)r * N + (k * 64 + lane) * 4);
        x[k].x = xc[rr2][k].x + xp[k].x; x[k].y = xc[rr2][k].y + xp[k].y;
        x[k].z = xc[rr2][k].z + xp[k].z; x[k].w = xc[rr2][k].w + xp[k].w;
        mx = fmaxf(mx, fmaxf(fmaxf(x[k].x, x[k].y), fmaxf(x[k].z, x[k].w)));
      }
#pragma unroll
      for (int o = 32; o; o >>= 1) mx = fmaxf(mx, __shfl_xor(mx, o));
      float sum = 0.f;
#pragma unroll
      for (int k = 0; k < 4; ++k) {
        x[k].x = __expf((x[k].x - mx) * SCL);
        x[k].y = __expf((x[k].y - mx) * SCL);
        x[k].z = __expf((x[k].z - mx) * SCL);
        x[k].w = __expf((x[k].w - mx) * SCL);
        sum += x[k].x + x[k].y + x[k].z + x[k].w;
      }
#pragma unroll
      for (int o = 32; o; o >>= 1) sum += __shfl_xor(sum, o);
      const float inv = 1.0f / sum;
#pragma unroll
      for (int k = 0; k < 4; ++k) {
        float4 y = {x[k].x * inv, x[k].y * inv, x[k].z * inv, x[k].w * inv};
        nt_store4(y, attnb + (size_t)r * N + (k * 64 + lane) * 4);
        *reinterpret_cast<float4*>(&sc[r * 1024 + ch[k] * 4]) = y;
      }
    }
  }
  block_sync_lds();

  // ---- phase 4: PV. waves split K halves; reduce via red ----
  {
    const bf16* Vbh = Vt + (size_t)bh * DH * N;
    const int wi = w >> 2, wj = w & 3;
    f32x4 acc = {};
    for (int kt = wi * 16; kt < wi * 16 + 16; ++kt) {
      const int p0 = (kt * 8 + g * 2) ^ (fr & 7);
      const float4 a0 = *reinterpret_cast<const float4*>(&sc[fr * 1024 + p0 * 4]);
      const float4 a1 =
          *reinterpret_cast<const float4*>(&sc[fr * 1024 + (p0 ^ 1) * 4]);
      const bf16x8 fb = *reinterpret_cast<const bf16x8*>(
          Vbh + (size_t)(wj * 16 + fr) * N + kt * 32 + kg);
      acc = mfma16(cvt8pk(a0, a1), fb, acc);
    }
    if (wi == 1) *reinterpret_cast<f32x4*>(&red[(wj * 64 + lane) * 4]) = acc;
    block_sync_lds();
    if (wi == 0) {
      const f32x4 o = *reinterpret_cast<const f32x4*>(&red[(wj * 64 + lane) * 4]);
      const int b_ = bh >> 4, h_ = bh & 15;
#pragma unroll
      for (int q = 0; q < 4; ++q) {
        const int row = i0 + g * 4 + q;
        const int dh = wj * 16 + fr;
        OA[((size_t)b_ * N + row) * D + h_ * DH + dh] = f2b(acc[q] + o[q]);
      }
    }
  }
}

}  // namespace

extern "C" void kernel_launch(void* const* d_in, const int* in_sizes, int n_in,
                              void* d_out, int out_size, void* d_ws,
                              size_t ws_size, hipStream_t stream) {
  (void)in_sizes; (void)n_in; (void)out_size; (void)ws_size;
  const float* query = (const float*)d_in[0];
  const float* key = (const float*)d_in[1];
  const float* value = (const float*)d_in[2];
  const float* pos_emb = (const float*)d_in[3];
  const float* Wq = (const float*)d_in[4];
  const float* bq = (const float*)d_in[5];
  const float* Wk = (const float*)d_in[6];
  const float* bk = (const float*)d_in[7];
  const float* Wv = (const float*)d_in[8];
  const float* bv = (const float*)d_in[9];
  const float* Wo = (const float*)d_in[10];
  const float* bo = (const float*)d_in[11];
  const float* Wp = (const float*)d_in[12];
  const float* ub = (const float*)d_in[13];
  const float* vb = (const float*)d_in[14];

  float* outF = (float*)d_out;
  float* attn = outF + (size_t)B * N * D;
  float* cont = attn + (size_t)BH * N * N;
  float* posS = cont + (size_t)BH * N * N;

  char* wsp = (char*)d_ws;
  auto alloc = [&](size_t elems) {
    bf16* p = (bf16*)wsp;
    wsp += elems * sizeof(bf16);
    return p;
  };
  bf16* Qu = alloc((size_t)BH * N * DH);
  bf16* Qv = alloc((size_t)BH * N * DH);
  bf16* Kb = alloc((size_t)BH * N * DH);
  bf16* Vt = alloc((size_t)BH * DH * N);
  bf16* Pb = alloc((size_t)BH * R2 * DH);
  bf16* OA = alloc((size_t)B * N * D);
  bf16* Wqt = alloc((size_t)D * D);
  bf16* Wkt = alloc((size_t)D * D);
  bf16* Wvt = alloc((size_t)D * D);
  bf16* Wpt = alloc((size_t)D * D);
  bf16* Wot = alloc((size_t)D * D);

  dim3 blk(256);
  transpose_cast_w<<<dim3(16, 16, 5), blk, 0, stream>>>(Wq, Wk, Wv, Wp, Wo, Wqt,
                                                        Wkt, Wvt, Wpt, Wot);
  // MEASUREMENT ROUND: proj_qkvp launched TWICE (idempotent — identical
  // writes from identical inputs). dur_us - 340 = T_proj directly.
  proj_qkvp<<<dim3(8, 32, 5), blk, 0, stream>>>(query, key, value, pos_emb,
                                                Wqt, Wkt, Wvt, Wpt, bq, bk, bv,
                                                ub, vb, Qu, Qv, Kb, Vt, Pb);
  proj_qkvp<<<dim3(8, 32, 5), blk, 0, stream>>>(query, key, value, pos_emb,
                                                Wqt, Wkt, Wvt, Wpt, bq, bk, bv,
                                                ub, vb, Qu, Qv, Kb, Vt, Pb);
  fused_attn<<<dim3(64, 64), dim3(512), 0, stream>>>(Qu, Qv, Kb, Pb, Vt, cont,
                                                     posS, attn, OA);
  proj_out<<<dim3(8, 32), blk, 0, stream>>>(OA, Wot, bo, outF);
}

// Round 11
// 337.977 us; speedup vs baseline: 1.2025x; 1.2025x over previous
//
#include <hip/hip_runtime.h>
#include <hip/hip_bf16.h>

typedef __bf16 bf16;
typedef __attribute__((ext_vector_type(8))) __bf16 bf16x8;
typedef __attribute__((ext_vector_type(4))) float f32x4;

#define DEV static __device__ __forceinline__

namespace {

constexpr int B = 4, N = 1024, D = 1024, H = 16, DH = 64;
constexpr int R2 = 2 * N - 1;   // 2047
constexpr int BH = B * H;       // 64
constexpr float SCL = 0.03125f; // 1/sqrt(1024)

// manual RNE f32 -> bf16 (scalar use)
DEV bf16 f2b(float x) {
  unsigned u = __builtin_bit_cast(unsigned, x);
  unsigned r = u + 0x7FFFu + ((u >> 16) & 1u);
  unsigned short h = (unsigned short)(r >> 16);
  return __builtin_bit_cast(bf16, h);
}

// HW packed cvt: 2 f32 -> 2 bf16 in one VALU op
DEV unsigned cvtpk(float lo, float hi) {
  unsigned r;
  asm("v_cvt_pk_bf16_f32 %0, %1, %2" : "=v"(r) : "v"(lo), "v"(hi));
  return r;
}

DEV bf16x8 cvt8pk(float4 a, float4 b) {
  union { unsigned u[4]; bf16x8 v; } r;
  r.u[0] = cvtpk(a.x, a.y); r.u[1] = cvtpk(a.z, a.w);
  r.u[2] = cvtpk(b.x, b.y); r.u[3] = cvtpk(b.z, b.w);
  return r.v;
}

DEV f32x4 mfma16(bf16x8 a, bf16x8 b, f32x4 c) {
  return __builtin_amdgcn_mfma_f32_16x16x32_bf16(a, b, c, 0, 0, 0);
}

// nontemporal 16B store via clang-native vector type
DEV void nt_store4(float4 v, float* p) {
  f32x4 x = {v.x, v.y, v.z, v.w};
  __builtin_nontemporal_store(x, reinterpret_cast<f32x4*>(p));
}

// LDS-only block barrier (no vmcnt drain)
DEV void block_sync_lds() {
  __builtin_amdgcn_sched_barrier(0);
  asm volatile("s_waitcnt lgkmcnt(0)" ::: "memory");
  __builtin_amdgcn_s_barrier();
  __builtin_amdgcn_sched_barrier(0);
}

// ---------- W transpose + cast: Wt[n][k] = bf16(W[k][n]) ----------
__global__ __launch_bounds__(256) void transpose_cast_w(
    const float* __restrict__ w0, const float* __restrict__ w1,
    const float* __restrict__ w2, const float* __restrict__ w3,
    const float* __restrict__ w4, bf16* __restrict__ t0, bf16* __restrict__ t1,
    bf16* __restrict__ t2, bf16* __restrict__ t3, bf16* __restrict__ t4) {
  const float* src; bf16* dst;
  switch (blockIdx.z) {
    case 0: src = w0; dst = t0; break;
    case 1: src = w1; dst = t1; break;
    case 2: src = w2; dst = t2; break;
    case 3: src = w3; dst = t3; break;
    default: src = w4; dst = t4; break;
  }
  __shared__ float tile[64][65];
  const int k0 = blockIdx.y * 64, n0 = blockIdx.x * 64;
  const int t = threadIdx.x, r = t >> 2, c0 = (t & 3) * 16;
  const float4* sp = reinterpret_cast<const float4*>(src + (size_t)(k0 + r) * D + n0 + c0);
#pragma unroll
  for (int q = 0; q < 4; ++q) {
    float4 v = sp[q];
    tile[r][c0 + q * 4 + 0] = v.x; tile[r][c0 + q * 4 + 1] = v.y;
    tile[r][c0 + q * 4 + 2] = v.z; tile[r][c0 + q * 4 + 3] = v.w;
  }
  __syncthreads();
  union { unsigned u[8]; uint4 q[2]; } pk;
#pragma unroll
  for (int e = 0; e < 8; ++e)
    pk.u[e] = cvtpk(tile[c0 + 2 * e][r], tile[c0 + 2 * e + 1][r]);
  uint4* dp = reinterpret_cast<uint4*>(dst + (size_t)(n0 + r) * D + k0 + c0);
  dp[0] = pk.q[0]; dp[1] = pk.q[1];
}

// ---------- projection GEMM core: C[128x128] tile of A[M x 1024] @ Bt^T -----
enum { M_QUV = 0, M_HEAD = 1, M_P = 2, M_OUT = 3, M_V = 4 };

template <bool ABF>
DEV void proj_core(char* smem, const void* __restrict__ Av,
                   const bf16* __restrict__ Bt, int M, int mt, int nt, int mode,
                   const float* __restrict__ bias, const float* __restrict__ ubp,
                   const float* __restrict__ vbp, bf16* __restrict__ dst0,
                   bf16* __restrict__ dst1, float* __restrict__ outf) {
  bf16* As = (bf16*)smem;
  bf16* Bs = (bf16*)(smem + 16384);
  float* ep = (float*)smem;  // aliased epilogue buffer, stride 132
  const int t = threadIdx.x;
  const int m0 = mt * 128, n0 = nt * 128;
  const int lane = t & 63, w = t >> 6;
  const int wi = w >> 1, wj = w & 1;
  const int fr = lane & 15, g = lane >> 4;
  f32x4 acc[4][4] = {};

  int rowc[4], ccc[4], rmc[4];
#pragma unroll
  for (int it = 0; it < 4; ++it) {
    const int chunk = it * 256 + t;
    rowc[it] = chunk >> 3; ccc[it] = chunk & 7;
    int rm = m0 + rowc[it]; rmc[it] = rm < M ? rm : M - 1;
  }
  float4 raf[4][2];
  bf16x8 rab[4];
  bf16x8 rbb[4];
  auto loadstep = [&](int k0) {
#pragma unroll
    for (int it = 0; it < 4; ++it) {
      if (ABF) {
        rab[it] = *reinterpret_cast<const bf16x8*>(
            (const bf16*)Av + (size_t)rmc[it] * D + k0 + ccc[it] * 8);
      } else {
        const float4* ap = reinterpret_cast<const float4*>(
            (const float*)Av + (size_t)rmc[it] * D + k0 + ccc[it] * 8);
        raf[it][0] = ap[0]; raf[it][1] = ap[1];
      }
      rbb[it] = *reinterpret_cast<const bf16x8*>(
          Bt + (size_t)(n0 + rowc[it]) * D + k0 + ccc[it] * 8);
    }
  };

  loadstep(0);
  for (int k0 = 0; k0 < D; k0 += 64) {
#pragma unroll
    for (int it = 0; it < 4; ++it) {
      const int row = rowc[it], cc = ccc[it];
      bf16x8 av;
      if (ABF) av = rab[it]; else av = cvt8pk(raf[it][0], raf[it][1]);
      *reinterpret_cast<bf16x8*>(&As[row * 64 + ((cc ^ (row & 7)) << 3)]) = av;
      *reinterpret_cast<bf16x8*>(&Bs[row * 64 + ((cc ^ (row & 7)) << 3)]) =
          rbb[it];
    }
    block_sync_lds();
    if (k0 + 64 < D) loadstep(k0 + 64);  // in flight across the next barrier
#pragma unroll
    for (int ks = 0; ks < 2; ++ks) {
      bf16x8 fa[4], fb[4];
#pragma unroll
      for (int i = 0; i < 4; ++i) {
        const int row = wi * 64 + i * 16 + fr;
        fa[i] = *reinterpret_cast<const bf16x8*>(
            &As[row * 64 + (((ks * 4 + g) ^ (row & 7)) << 3)]);
      }
#pragma unroll
      for (int j = 0; j < 4; ++j) {
        const int row = wj * 64 + j * 16 + fr;
        fb[j] = *reinterpret_cast<const bf16x8*>(
            &Bs[row * 64 + (((ks * 4 + g) ^ (row & 7)) << 3)]);
      }
#pragma unroll
      for (int i = 0; i < 4; ++i)
#pragma unroll
        for (int j = 0; j < 4; ++j) acc[i][j] = mfma16(fa[i], fb[j], acc[i][j]);
    }
    block_sync_lds();
  }
  // ---- epilogue: 2 passes of 64 rows via f32 LDS (stride 132), coalesced ----
#pragma unroll
  for (int p = 0; p < 2; ++p) {
    block_sync_lds();
    if (wi == p) {
#pragma unroll
      for (int i = 0; i < 4; ++i)
#pragma unroll
        for (int j = 0; j < 4; ++j)
#pragma unroll
          for (int q = 0; q < 4; ++q)
            ep[(i * 16 + g * 4 + q) * 132 + wj * 64 + j * 16 + fr] =
                acc[i][j][q];
    }
    block_sync_lds();
    if (mode == M_V) {
      const int col = t >> 1, seg = t & 1;
      const int cg = n0 + col;
      const int h_ = cg >> 6, dh = cg & 63;
      const int b_ = m0 >> 10;
      const int tok0 = (m0 & 1023) + p * 64 + seg * 32;
      const float bvv = bias[cg];
      unsigned pk[16];
#pragma unroll
      for (int e = 0; e < 16; ++e) {
        const float v0 = ep[(seg * 32 + 2 * e + 0) * 132 + col] + bvv;
        const float v1 = ep[(seg * 32 + 2 * e + 1) * 132 + col] + bvv;
        pk[e] = cvtpk(v0, v1);
      }
      bf16* dp = dst0 + ((size_t)(b_ * H + h_) * DH + dh) * N + tok0;
#pragma unroll
      for (int kk = 0; kk < 4; ++kk)
        reinterpret_cast<uint4*>(dp)[kk] =
            *reinterpret_cast<const uint4*>(&pk[kk * 4]);
      continue;
    }
    const int lr = t >> 2, cl = (t & 3) * 32;
    const int m = m0 + p * 64 + lr;
    if (m < M) {
      float v[32];
#pragma unroll
      for (int kk = 0; kk < 8; ++kk) {
        const float4 f =
            *reinterpret_cast<const float4*>(&ep[lr * 132 + cl + kk * 4]);
        v[kk * 4 + 0] = f.x; v[kk * 4 + 1] = f.y;
        v[kk * 4 + 2] = f.z; v[kk * 4 + 3] = f.w;
      }
      const int cg0 = n0 + cl;
      if (mode == M_OUT) {
        float* op = outf + (size_t)m * D + cg0;
#pragma unroll
        for (int kk = 0; kk < 8; ++kk) {
          float4 f = {v[kk * 4] + bias[cg0 + kk * 4],
                      v[kk * 4 + 1] + bias[cg0 + kk * 4 + 1],
                      v[kk * 4 + 2] + bias[cg0 + kk * 4 + 2],
                      v[kk * 4 + 3] + bias[cg0 + kk * 4 + 3]};
          nt_store4(f, op + kk * 4);
        }
      } else if (mode == M_P) {
        const int b_ = m / R2, r_ = m - b_ * R2;
        const int h_ = cg0 >> 6, dh0 = cg0 & 63;
        bf16* dp = dst0 + (((size_t)(b_ * H + h_)) * R2 + r_) * DH + dh0;
        unsigned pk[16];
#pragma unroll
        for (int e = 0; e < 16; ++e) pk[e] = cvtpk(v[2 * e], v[2 * e + 1]);
#pragma unroll
        for (int kk = 0; kk < 4; ++kk)
          reinterpret_cast<uint4*>(dp)[kk] =
              *reinterpret_cast<const uint4*>(&pk[kk * 4]);
      } else {
        const int b_ = m >> 10, ii = m & (N - 1);
        const int h_ = cg0 >> 6, dh0 = cg0 & 63;
        const size_t o = (((size_t)(b_ * H + h_)) * N + ii) * DH + dh0;
        if (mode == M_QUV) {
          unsigned pku[16], pkv[16];
#pragma unroll
          for (int e = 0; e < 16; ++e) {
            const float b0 = bias[cg0 + 2 * e], b1 = bias[cg0 + 2 * e + 1];
            pku[e] = cvtpk(v[2 * e] + b0 + ubp[cg0 + 2 * e],
                           v[2 * e + 1] + b1 + ubp[cg0 + 2 * e + 1]);
            pkv[e] = cvtpk(v[2 * e] + b0 + vbp[cg0 + 2 * e],
                           v[2 * e + 1] + b1 + vbp[cg0 + 2 * e + 1]);
          }
#pragma unroll
          for (int kk = 0; kk < 4; ++kk) {
            reinterpret_cast<uint4*>(dst0 + o)[kk] =
                *reinterpret_cast<const uint4*>(&pku[kk * 4]);
            reinterpret_cast<uint4*>(dst1 + o)[kk] =
                *reinterpret_cast<const uint4*>(&pkv[kk * 4]);
          }
        } else {
          unsigned pk[16];
#pragma unroll
          for (int e = 0; e < 16; ++e)
            pk[e] = cvtpk(v[2 * e] + bias[cg0 + 2 * e],
                          v[2 * e + 1] + bias[cg0 + 2 * e + 1]);
#pragma unroll
          for (int kk = 0; kk < 4; ++kk)
            reinterpret_cast<uint4*>(dst0 + o)[kk] =
                *reinterpret_cast<const uint4*>(&pk[kk * 4]);
        }
      }
    }
  }
}

// merged projections: grid (8, 32, 5); XCD x owns a contiguous M-chunk per
// z-slice. z: 0=Q(QUV) 1=K 2=V(->Vt direct) 3,4=P halves.
__global__ __launch_bounds__(256, 3) void proj_qkvp(
    const float* __restrict__ query, const float* __restrict__ key,
    const float* __restrict__ value, const float* __restrict__ pos_emb,
    const bf16* __restrict__ Wqt, const bf16* __restrict__ Wkt,
    const bf16* __restrict__ Wvt, const bf16* __restrict__ Wpt,
    const float* __restrict__ bq, const float* __restrict__ bk,
    const float* __restrict__ bv, const float* __restrict__ ub,
    const float* __restrict__ vbp, bf16* __restrict__ Qu,
    bf16* __restrict__ Qv, bf16* __restrict__ Kb, bf16* __restrict__ Vt,
    bf16* __restrict__ Pb) {
  __shared__ __align__(16) char smem[34048];
  const int z = blockIdx.z, x = blockIdx.x, y = blockIdx.y;
  const int nt = y & 7;
  const int mt = x * 4 + (y >> 3);
  switch (z) {
    case 0:
      proj_core<false>(smem, query, Wqt, B * N, mt, nt, M_QUV, bq, ub, vbp, Qu,
                       Qv, nullptr);
      break;
    case 1:
      proj_core<false>(smem, key, Wkt, B * N, mt, nt, M_HEAD, bk, nullptr,
                       nullptr, Kb, nullptr, nullptr);
      break;
    case 2:
      proj_core<false>(smem, value, Wvt, B * N, mt, nt, M_V, bv, nullptr,
                       nullptr, Vt, nullptr, nullptr);
      break;
    case 3:
      proj_core<false>(smem, pos_emb, Wpt, B * R2, mt, nt, M_P, nullptr,
                       nullptr, nullptr, Pb, nullptr, nullptr);
      break;
    default:
      proj_core<false>(smem, pos_emb, Wpt, B * R2, 32 + mt, nt, M_P, nullptr,
                       nullptr, nullptr, Pb, nullptr, nullptr);
      break;
  }
}

__global__ __launch_bounds__(256, 2) void proj_out(const bf16* __restrict__ OA,
                                                   const bf16* __restrict__ Wot,
                                                   const float* __restrict__ bo,
                                                   float* __restrict__ outF) {
  __shared__ __align__(16) char smem[34048];
  const int nt = blockIdx.y & 7;
  const int mt = blockIdx.x * 4 + (blockIdx.y >> 3);
  proj_core<true>(smem, OA, Wot, B * N, mt, nt, M_OUT, bo, nullptr, nullptr,
                  nullptr, nullptr, outF);
}

// ---------- fused: content + pos(shifted) + softmax + PV ---------------------
// Store streams spread across phases: cont in phase2b (under pos MFMA),
// posS rows r=w*2 in phase3, posS rows r=w*2+1 interleaved in phase4's PV
// loop (fills the former store-free tail), attn in phase3.
constexpr int RB = 16;

DEV int SIDX(int r, int c) {
  return r * 1024 + (((c >> 2) ^ (r & 7)) << 2) + (c & 3);
}

__global__ __launch_bounds__(512, 4) void fused_attn(
    const bf16* __restrict__ Qu, const bf16* __restrict__ Qv,
    const bf16* __restrict__ Kb, const bf16* __restrict__ Pb,
    const bf16* __restrict__ Vt, float* __restrict__ cont,
    float* __restrict__ posS, float* __restrict__ attn,
    bf16* __restrict__ OA) {
  __shared__ float sc[RB * 1024];  // 64 KB
  __shared__ float red[1024];      // PV partial reduce
  const int bid0 = blockIdx.y * 64 + blockIdx.x;
  const int bid = (bid0 & 7) * 512 + (bid0 >> 3);  // XCD owns 8 heads
  const int bh = bid >> 6, i0 = (bid & 63) * RB;
  const int t = threadIdx.x, lane = t & 63, w = t >> 6;
  const int fr = lane & 15, g = lane >> 4, kg = g * 8;

  // ---- phase 1: content scores -> sc ----
  {
    const bf16* Qub = Qu + ((size_t)bh * N + i0) * DH;
    const bf16* Kbh = Kb + (size_t)bh * N * DH;
    const bf16x8 fa0 = *reinterpret_cast<const bf16x8*>(Qub + (size_t)fr * DH + kg);
    const bf16x8 fa1 = *reinterpret_cast<const bf16x8*>(Qub + (size_t)fr * DH + 32 + kg);
#pragma unroll
    for (int tt = 0; tt < 8; ++tt) {
      const int ct = (w * 8 + tt) * 16;
      const bf16x8 fb0 =
          *reinterpret_cast<const bf16x8*>(Kbh + (size_t)(ct + fr) * DH + kg);
      const bf16x8 fb1 =
          *reinterpret_cast<const bf16x8*>(Kbh + (size_t)(ct + fr) * DH + 32 + kg);
      f32x4 acc = {};
      acc = mfma16(fa0, fb0, acc);
      acc = mfma16(fa1, fb1, acc);
      const int c = ct + fr;
#pragma unroll
      for (int q = 0; q < 4; ++q) sc[SIDX(g * 4 + q, c)] = acc[q];
    }
  }
  block_sync_lds();

  // ---- phase 2a: read content rows to regs (LDS only) ----
  float4 xc[2][4];
#pragma unroll
  for (int rr2 = 0; rr2 < 2; ++rr2) {
    const int r = w * 2 + rr2;
#pragma unroll
    for (int k = 0; k < 4; ++k) {
      const int ch = (k * 64 + lane) ^ (r & 7);
      xc[rr2][k] = *reinterpret_cast<const float4*>(&sc[r * 1024 + ch * 4]);
    }
  }
  block_sync_lds();

  // ---- phase 2b: issue cont stores (fly under MFMA); pos scores -> sc ----
  {
    float* contb = cont + ((size_t)bh * N + i0) * N;
#pragma unroll
    for (int rr2 = 0; rr2 < 2; ++rr2) {
      const int r = w * 2 + rr2;
#pragma unroll
      for (int k = 0; k < 4; ++k)
        nt_store4(xc[rr2][k], contb + (size_t)r * N + (k * 64 + lane) * 4);
    }
    const bf16* Qvb = Qv + ((size_t)bh * N + i0) * DH;
    const bf16* Pbh = Pb + (size_t)bh * R2 * DH;
    const bf16x8 fa0 = *reinterpret_cast<const bf16x8*>(Qvb + (size_t)fr * DH + kg);
    const bf16x8 fa1 = *reinterpret_cast<const bf16x8*>(Qvb + (size_t)fr * DH + 32 + kg);
    const int Rlo = (N - RB) - i0;
    for (int tt = w; tt < 65; tt += 8) {
      const int rr = Rlo + tt * 16 + fr;
      const int rc = rr < R2 ? rr : R2 - 1;
      const bf16x8 fb0 =
          *reinterpret_cast<const bf16x8*>(Pbh + (size_t)rc * DH + kg);
      const bf16x8 fb1 =
          *reinterpret_cast<const bf16x8*>(Pbh + (size_t)rc * DH + 32 + kg);
      f32x4 acc = {};
      acc = mfma16(fa0, fb0, acc);
      acc = mfma16(fa1, fb1, acc);
#pragma unroll
      for (int q = 0; q < 4; ++q) {
        const int r = g * 4 + q;
        const int jj = rr - (N - 1) + i0 + r;
        if (rr < R2 && jj >= 0 && jj < N) sc[SIDX(r, jj)] = acc[q];
      }
    }
  }
  block_sync_lds();

  // ---- phase 3: softmax; store attn; store posS row r=w*2; keep row w*2+1 --
  float4 xp1[4];  // posS values of row w*2+1, stored during phase 4
  {
    float* posb = posS + ((size_t)bh * N + i0) * N;
    float* attnb = attn + ((size_t)bh * N + i0) * N;
#pragma unroll
    for (int rr2 = 0; rr2 < 2; ++rr2) {
      const int r = w * 2 + rr2;
      float4 xp[4], x[4];
      int ch[4];
#pragma unroll
      for (int k = 0; k < 4; ++k) {
        ch[k] = (k * 64 + lane) ^ (r & 7);
        xp[k] = *reinterpret_cast<const float4*>(&sc[r * 1024 + ch[k] * 4]);
      }
      float mx = -1e30f;
#pragma unroll
      for (int k = 0; k < 4; ++k) {
        if (rr2 == 0) {
          nt_store4(xp[k], posb + (size_t)r * N + (k * 64 + lane) * 4);
        } else {
          xp1[k] = xp[k];
        }
        x[k].x = xc[rr2][k].x + xp[k].x; x[k].y = xc[rr2][k].y + xp[k].y;
        x[k].z = xc[rr2][k].z + xp[k].z; x[k].w = xc[rr2][k].w + xp[k].w;
        mx = fmaxf(mx, fmaxf(fmaxf(x[k].x, x[k].y), fmaxf(x[k].z, x[k].w)));
      }
#pragma unroll
      for (int o = 32; o; o >>= 1) mx = fmaxf(mx, __shfl_xor(mx, o));
      float sum = 0.f;
#pragma unroll
      for (int k = 0; k < 4; ++k) {
        x[k].x = __expf((x[k].x - mx) * SCL);
        x[k].y = __expf((x[k].y - mx) * SCL);
        x[k].z = __expf((x[k].z - mx) * SCL);
        x[k].w = __expf((x[k].w - mx) * SCL);
        sum += x[k].x + x[k].y + x[k].z + x[k].w;
      }
#pragma unroll
      for (int o = 32; o; o >>= 1) sum += __shfl_xor(sum, o);
      const float inv = 1.0f / sum;
#pragma unroll
      for (int k = 0; k < 4; ++k) {
        float4 y = {x[k].x * inv, x[k].y * inv, x[k].z * inv, x[k].w * inv};
        nt_store4(y, attnb + (size_t)r * N + (k * 64 + lane) * 4);
        *reinterpret_cast<float4*>(&sc[r * 1024 + ch[k] * 4]) = y;
      }
    }
  }
  block_sync_lds();

  // ---- phase 4: PV (setprio) with posS row w*2+1 stores interleaved --------
  {
    const bf16* Vbh = Vt + (size_t)bh * DH * N;
    const int wi = w >> 2, wj = w & 3;
    float* posb1 =
        posS + ((size_t)bh * N + i0 + w * 2 + 1) * N + lane * 4;
    f32x4 acc = {};
    __builtin_amdgcn_s_setprio(1);
    for (int kt = wi * 16; kt < wi * 16 + 16; ++kt) {
      const int lt = kt - wi * 16;
      if ((lt & 3) == 0) {
        const int k = lt >> 2;  // 0..3
        nt_store4(xp1[k], posb1 + k * 256);
      }
      const int p0 = (kt * 8 + g * 2) ^ (fr & 7);
      const float4 a0 = *reinterpret_cast<const float4*>(&sc[fr * 1024 + p0 * 4]);
      const float4 a1 =
          *reinterpret_cast<const float4*>(&sc[fr * 1024 + (p0 ^ 1) * 4]);
      const bf16x8 fb = *reinterpret_cast<const bf16x8*>(
          Vbh + (size_t)(wj * 16 + fr) * N + kt * 32 + kg);
      acc = mfma16(cvt8pk(a0, a1), fb, acc);
    }
    __builtin_amdgcn_s_setprio(0);
    if (wi == 1) *reinterpret_cast<f32x4*>(&red[(wj * 64 + lane) * 4]) = acc;
    block_sync_lds();
    if (wi == 0) {
      const f32x4 o = *reinterpret_cast<const f32x4*>(&red[(wj * 64 + lane) * 4]);
      const int b_ = bh >> 4, h_ = bh & 15;
#pragma unroll
      for (int q = 0; q < 4; ++q) {
        const int row = i0 + g * 4 + q;
        const int dh = wj * 16 + fr;
        OA[((size_t)b_ * N + row) * D + h_ * DH + dh] = f2b(acc[q] + o[q]);
      }
    }
  }
}

}  // namespace

extern "C" void kernel_launch(void* const* d_in, const int* in_sizes, int n_in,
                              void* d_out, int out_size, void* d_ws,
                              size_t ws_size, hipStream_t stream) {
  (void)in_sizes; (void)n_in; (void)out_size; (void)ws_size;
  const float* query = (const float*)d_in[0];
  const float* key = (const float*)d_in[1];
  const float* value = (const float*)d_in[2];
  const float* pos_emb = (const float*)d_in[3];
  const float* Wq = (const float*)d_in[4];
  const float* bq = (const float*)d_in[5];
  const float* Wk = (const float*)d_in[6];
  const float* bk = (const float*)d_in[7];
  const float* Wv = (const float*)d_in[8];
  const float* bv = (const float*)d_in[9];
  const float* Wo = (const float*)d_in[10];
  const float* bo = (const float*)d_in[11];
  const float* Wp = (const float*)d_in[12];
  const float* ub = (const float*)d_in[13];
  const float* vb = (const float*)d_in[14];

  float* outF = (float*)d_out;
  float* attn = outF + (size_t)B * N * D;
  float* cont = attn + (size_t)BH * N * N;
  float* posS = cont + (size_t)BH * N * N;

  char* wsp = (char*)d_ws;
  auto alloc = [&](size_t elems) {
    bf16* p = (bf16*)wsp;
    wsp += elems * sizeof(bf16);
    return p;
  };
  bf16* Qu = alloc((size_t)BH * N * DH);
  bf16* Qv = alloc((size_t)BH * N * DH);
  bf16* Kb = alloc((size_t)BH * N * DH);
  bf16* Vt = alloc((size_t)BH * DH * N);
  bf16* Pb = alloc((size_t)BH * R2 * DH);
  bf16* OA = alloc((size_t)B * N * D);
  bf16* Wqt = alloc((size_t)D * D);
  bf16* Wkt = alloc((size_t)D * D);
  bf16* Wvt = alloc((size_t)D * D);
  bf16* Wpt = alloc((size_t)D * D);
  bf16* Wot = alloc((size_t)D * D);

  dim3 blk(256);
  transpose_cast_w<<<dim3(16, 16, 5), blk, 0, stream>>>(Wq, Wk, Wv, Wp, Wo, Wqt,
                                                        Wkt, Wvt, Wpt, Wot);
  proj_qkvp<<<dim3(8, 32, 5), blk, 0, stream>>>(query, key, value, pos_emb,
                                                Wqt, Wkt, Wvt, Wpt, bq, bk, bv,
                                                ub, vb, Qu, Qv, Kb, Vt, Pb);
  fused_attn<<<dim3(64, 64), dim3(512), 0, stream>>>(Qu, Qv, Kb, Pb, Vt, cont,
                                                     posS, attn, OA);
  proj_out<<<dim3(8, 32), blk, 0, stream>>>(OA, Wot, bo, outF);
}